// Round 12
// baseline (134.382 us; speedup 1.0000x reference)
//
#include <hip/hip_runtime.h>
#include <hip/hip_bf16.h>

#define BATCH 4
#define SEQ 4096
#define DMODEL 2048
#define HD 128
#define BS (BATCH*SEQ)

typedef __attribute__((ext_vector_type(8))) short short8;
typedef __attribute__((ext_vector_type(4))) float f32x4;
typedef __attribute__((ext_vector_type(4))) float float4v;
typedef unsigned short u16;
typedef unsigned int u32;

#define LOG2E 1.4426950408889634f
#define SCALE 0.08838834764831845f /* 1/sqrt(128) */

__device__ __forceinline__ u16 f2bf(float f){
  u32 u = __builtin_bit_cast(u32, f);
  u32 r = (u + 0x7FFFu + ((u >> 16) & 1u)) >> 16;
  return (u16)r;
}
__device__ __forceinline__ float bf2f(u16 b){
  u32 u = ((u32)b) << 16;
  return __builtin_bit_cast(float, u);
}

__device__ __forceinline__ void gload16(const void* gptr, void* lptr){
  __builtin_amdgcn_global_load_lds((const __attribute__((address_space(1))) void*)gptr,
                                   (__attribute__((address_space(3))) void*)lptr, 16, 0, 0);
}

// ---------------- trig table + weight convert, merged ----------------
__global__ __launch_bounds__(256) void k_prep(float2* __restrict__ tab,
                                              const float* __restrict__ wq, const float* __restrict__ wk,
                                              const float* __restrict__ wv, u16* __restrict__ wb){
  int bidx = blockIdx.x;
  if (bidx < 1024){
    int i = bidx*256 + threadIdx.x;            // 4096*64 total
    int s = i >> 6, j = i & 63;
    float invf = (float)pow(10000.0, -(double)j/64.0);
    float ang  = (float)s * invf;              // mimic fp32 reference rounding of the angle
    double a = (double)ang;
    tab[i] = make_float2((float)cos(a), (float)sin(a));
  } else {
    int i = (bidx - 1024)*256 + threadIdx.x;   // 3*262144 total
    int m = i >> 18; int r = i & 262143;
    const float* s = (m==0) ? wq : ((m==1) ? wk : wv);
    wb[i] = f2bf(s[r]);
  }
}

// ---------------- x fp32 -> bf16 ----------------
__global__ __launch_bounds__(256) void k_cvtx(const float* __restrict__ x, u16* __restrict__ xb){
  size_t i = (size_t)blockIdx.x*256 + threadIdx.x;   // each handles 8 elems; grid exact
  const float4v* xp = (const float4v*)x;
  float4v a = xp[i*2], c = xp[i*2+1];
  short8 o;
  o[0]=(short)f2bf(a[0]); o[1]=(short)f2bf(a[1]); o[2]=(short)f2bf(a[2]); o[3]=(short)f2bf(a[3]);
  o[4]=(short)f2bf(c[0]); o[5]=(short)f2bf(c[1]); o[6]=(short)f2bf(c[2]); o[7]=(short)f2bf(c[3]);
  *(short8*)(xb + i*8) = o;
}

// ---------------- QKV projection GEMM + fused RoPE / V-transpose epilogue ----------------
// BM=64, BN=128, BK=64: grid (3,256) = 768 blocks = 3 blocks/CU (cross-block latency hiding,
// the m97 property our BM=128 grid-384 version lacked). LDS 24KB (A 8K + W 16K), 2 barriers/step.
// Wave tile: 64 rows x two 16-col stripes (wn*16, wn*16+64) -> RoPE pairs lane-local.
__global__ __launch_bounds__(256,3) void k_gemm(
    const u16* __restrict__ xb, const u16* __restrict__ wb, const float2* __restrict__ tab,
    u16* __restrict__ qb, u16* __restrict__ kb, u16* __restrict__ vt)
{
  __shared__ char lds[24576];   // [0,8K) A 64x64 bf16 swz; [8K,24K) W 128x64 bf16 swz
  const int tid = threadIdx.x;
  const int wsel = blockIdx.x;                 // 0..2 (Q,K,V) — adjacent blocks share A-tile
  const int mg = blockIdx.y;                   // 0..255
  const size_t M0 = (size_t)mg * 64;
  const u16* Wm = wb + (size_t)wsel * (HD*DMODEL);
  const int w = tid >> 6, lane = tid & 63, lr = lane & 15, lg = lane >> 4;

  f32x4 acc[4][2];
  #pragma unroll
  for (int i=0;i<4;i++)
    #pragma unroll
    for (int j=0;j<2;j++) acc[i][j] = f32x4{0.f,0.f,0.f,0.f};

  const int Lb = tid*16;
  // A staging: 2 chunks of the 64x64 bf16 tile
  int asrow[2], asoff[2];
  #pragma unroll
  for (int i=0;i<2;i++){
    int L = i*4096 + Lb;
    int row = L >> 7, cb = L & 127;
    asrow[i] = row; asoff[i] = (cb ^ ((row & 7) << 4)) >> 1;
  }
  // W staging: 4 chunks of the 128x64 bf16 tile
  int wsrow[4], wsoff[4];
  #pragma unroll
  for (int i=0;i<4;i++){
    int L = i*4096 + Lb;
    int row = L >> 7, cb = L & 127;
    wsrow[i] = row; wsoff[i] = (cb ^ ((row & 7) << 4)) >> 1;
  }

  for (int k0 = 0; k0 < DMODEL; k0 += 64){
    #pragma unroll
    for (int i=0;i<2;i++)
      gload16(xb + (M0 + asrow[i])*DMODEL + k0 + asoff[i], lds + i*4096 + Lb);
    #pragma unroll
    for (int i=0;i<4;i++)
      gload16(Wm + (size_t)wsrow[i]*DMODEL + k0 + wsoff[i], lds + 8192 + i*4096 + Lb);
    __syncthreads();

    short8 af[4][2], wf[2][2];
    #pragma unroll
    for (int rf=0; rf<4; rf++)
      #pragma unroll
      for (int ks=0; ks<2; ks++){
        int r = rf*16 + lr;
        af[rf][ks] = *(const short8*)(lds + r*128 + ((ks*64 + lg*16) ^ ((r&7)<<4)));
      }
    #pragma unroll
    for (int nf=0; nf<2; nf++)
      #pragma unroll
      for (int ks=0; ks<2; ks++){
        int r = w*16 + nf*64 + lr;
        wf[nf][ks] = *(const short8*)(lds + 8192 + r*128 + ((ks*64 + lg*16) ^ ((r&7)<<4)));
      }
    #pragma unroll
    for (int rf=0; rf<4; rf++)
      #pragma unroll
      for (int nf=0; nf<2; nf++){
        acc[rf][nf] = __builtin_amdgcn_mfma_f32_16x16x32_bf16(af[rf][0], wf[nf][0], acc[rf][nf], 0,0,0);
        acc[rf][nf] = __builtin_amdgcn_mfma_f32_16x16x32_bf16(af[rf][1], wf[nf][1], acc[rf][nf], 0,0,0);
      }
    __syncthreads();
  }

  if (wsel < 2){
    u16* dst = (wsel == 0) ? qb : kb;
    #pragma unroll
    for (int rf=0; rf<4; rf++){
      #pragma unroll
      for (int reg=0; reg<4; reg++){
        size_t grow = M0 + rf*16 + lg*4 + reg;
        int spos = (int)(grow & (SEQ-1));
        int j = w*16 + lr;                    // 0..63
        float2 cs = tab[spos*64 + j];
        float lo = acc[rf][0][reg];
        float hi = acc[rf][1][reg];
        dst[grow*HD + j]      = f2bf(lo*cs.x - hi*cs.y);
        dst[grow*HD + j + 64] = f2bf(hi*cs.x + lo*cs.y);
      }
    }
  } else {
    #pragma unroll
    for (int rf=0; rf<4; rf++)
      #pragma unroll
      for (int reg=0; reg<4; reg++){
        size_t grow = M0 + rf*16 + lg*4 + reg;
        size_t b = grow >> 12;
        size_t spos = grow & (SEQ-1);
        #pragma unroll
        for (int nf=0; nf<2; nf++){
          int col = w*16 + nf*64 + lr;
          vt[(b*HD + col)*SEQ + spos] = f2bf(acc[rf][nf][reg]);
        }
      }
  }
}

// ---------------- causal flash attention, 4-way KV split (flash-decoding) ----------------
// grid 1024: (batch, 64-row q-tile, kv-split). 4 waves x 16 q-rows share staged lK/lV.
// LDS 40KB -> 4 blocks/CU -> 16 waves/CU. Partials (O bf16, ml fp32) to workspace.
__global__ __launch_bounds__(256) void k_attn(
    const u16* __restrict__ qbuf, const u16* __restrict__ kb, const u16* __restrict__ vt,
    u16* __restrict__ Opart, float2* __restrict__ ml)
{
  __shared__ u16 lK[64*128];    // byte = kv*256 + (cb ^ ((kv&7)<<4))
  __shared__ u16 lV[128*64];    // byte = d*128  + (cb ^ ((d&7)<<4))
  __shared__ u16 lP[4][16*64];  // per-wave, byte = r*128 + (cb ^ ((r&7)<<4))
  const int tid = threadIdx.x;
  const int bid = blockIdx.x;
  const int x = bid & 7, idx = bid >> 3;
  const int b = x >> 1, half = x & 1;
  const int qt = 63 - (idx >> 1);              // heavy tiles first
  const int sp = (idx & 1) + 2*half;           // kv-split 0..3
  const int qbn = b*64 + qt;                   // 0..255
  const int w = tid >> 6, lane = tid & 63, lr = lane & 15, lg = lane >> 4;

  // balanced contiguous partition of tiles [0, qt] into 4 chunks
  const int n = qt + 1, cbase = n >> 2, crem = n & 3;
  const int cnt = cbase + (sp < crem ? 1 : 0);
  const int klo = sp*cbase + (sp < crem ? sp : crem);
  const int khi = klo + cnt;
  const size_t prow0 = ((size_t)qbn*4 + sp)*64;

  if (cnt == 0){                               // empty split: mark and exit (block-uniform)
    if (lr == 0){
      #pragma unroll
      for (int reg=0; reg<4; reg++)
        ml[prow0 + w*16 + lg*4 + reg] = make_float2(-1e30f, 0.f);
    }
    return;
  }

  const size_t qrow = (size_t)b*SEQ + qt*64 + w*16 + lr;
  short8 aq[4];
  #pragma unroll
  for (int ks=0; ks<4; ks++)
    aq[ks] = *(const short8*)(qbuf + qrow*HD + ks*32 + lg*8);

  f32x4 accO[8];
  #pragma unroll
  for (int i=0;i<8;i++) accO[i] = f32x4{0.f,0.f,0.f,0.f};
  float m2[4]   = {-1e30f,-1e30f,-1e30f,-1e30f};
  float lsum[4] = {0.f,0.f,0.f,0.f};

  const int Lb = tid*16;
  const float cfac = SCALE * LOG2E;

  for (int kt = klo; kt < khi; kt++){
    #pragma unroll
    for (int i=0;i<4;i++){
      int L = i*4096 + Lb;
      { int row = L >> 8, cb = L & 255;
        int scb = cb ^ ((row & 7) << 4);
        gload16(kb + ((size_t)b*SEQ + kt*64 + row)*HD + (scb>>1), ((char*)lK) + L); }
      { int row = L >> 7, cb = L & 127;
        int scb = cb ^ ((row & 7) << 4);
        gload16(vt + ((size_t)b*HD + row)*SEQ + kt*64 + (scb>>1), ((char*)lV) + L); }
    }
    __syncthreads();

    // S = Q K^T  (16 q-rows x 64 kv) in log2-domain units
    f32x4 sc[4];
    #pragma unroll
    for (int nf=0; nf<4; nf++){
      sc[nf] = f32x4{0.f,0.f,0.f,0.f};
      #pragma unroll
      for (int ks=0; ks<4; ks++){
        int r = nf*16 + lr;
        int byte = r*256 + ((ks*64 + lg*16) ^ ((r&7)<<4));
        short8 bk = *(const short8*)((const char*)lK + byte);
        sc[nf] = __builtin_amdgcn_mfma_f32_16x16x32_bf16(aq[ks], bk, sc[nf], 0,0,0);
      }
      sc[nf] *= cfac;
    }
    if (kt == qt){                            // diagonal tile: causal mask
      #pragma unroll
      for (int nf=0; nf<4; nf++)
        #pragma unroll
        for (int reg=0; reg<4; reg++){
          int col = nf*16 + lr;
          int row = w*16 + lg*4 + reg;
          if (col > row) sc[nf][reg] = -1e30f;
        }
    }
    float al[4];
    #pragma unroll
    for (int reg=0; reg<4; reg++){
      float v = fmaxf(fmaxf(sc[0][reg], sc[1][reg]), fmaxf(sc[2][reg], sc[3][reg]));
      v = fmaxf(v, __shfl_xor(v, 1));
      v = fmaxf(v, __shfl_xor(v, 2));
      v = fmaxf(v, __shfl_xor(v, 4));
      v = fmaxf(v, __shfl_xor(v, 8));
      float mnew = fmaxf(m2[reg], v);
      al[reg] = exp2f(m2[reg] - mnew);
      m2[reg] = mnew;
    }
    float prs[4] = {0.f,0.f,0.f,0.f};
    #pragma unroll
    for (int nf=0; nf<4; nf++)
      #pragma unroll
      for (int reg=0; reg<4; reg++){
        float p = exp2f(sc[nf][reg] - m2[reg]);
        prs[reg] += p;
        int r = lg*4 + reg;
        int byte = r*128 + ((nf*32 + lr*2) ^ ((r&7)<<4));
        *(u16*)(((char*)lP[w]) + byte) = f2bf(p);
      }
    f32x4 alv = f32x4{al[0], al[1], al[2], al[3]};
    #pragma unroll
    for (int reg=0; reg<4; reg++){
      float v = prs[reg];
      v += __shfl_xor(v, 1);
      v += __shfl_xor(v, 2);
      v += __shfl_xor(v, 4);
      v += __shfl_xor(v, 8);
      lsum[reg] = lsum[reg]*al[reg] + v;
    }
    #pragma unroll
    for (int cf=0; cf<8; cf++) accO[cf] *= alv;

    short8 pa[2];
    #pragma unroll
    for (int ks=0; ks<2; ks++){
      int byte = lr*128 + ((ks*64 + lg*16) ^ ((lr&7)<<4));
      pa[ks] = *(const short8*)(((const char*)lP[w]) + byte);
    }
    #pragma unroll
    for (int cf=0; cf<8; cf++){
      #pragma unroll
      for (int ks=0; ks<2; ks++){
        int d = cf*16 + lr;
        int byte = d*128 + ((ks*64 + lg*16) ^ ((d&7)<<4));
        short8 bv = *(const short8*)(((const char*)lV) + byte);
        accO[cf] = __builtin_amdgcn_mfma_f32_16x16x32_bf16(pa[ks], bv, accO[cf], 0,0,0);
      }
    }
    __syncthreads();
  }

  // partial epilogue: bf16 accO + (m, l) per row
  #pragma unroll
  for (int reg=0; reg<4; reg++){
    size_t pr = prow0 + w*16 + lg*4 + reg;
    #pragma unroll
    for (int cf=0; cf<8; cf++)
      Opart[pr*HD + cf*16 + lr] = f2bf(accO[cf][reg]);
  }
  if (lr == 0){
    #pragma unroll
    for (int reg=0; reg<4; reg++)
      ml[prow0 + w*16 + lg*4 + reg] = make_float2(m2[reg], lsum[reg]);
  }
}

// ---------------- combine partials: out = sum_s O_s * 2^(m_s-M) / L ----------------
// grid 1024: 16 rows/block, 8 cols/thread (bf16 Opart short8 reads).
__global__ __launch_bounds__(256) void k_comb(
    const u16* __restrict__ Opart, const float2* __restrict__ ml, float* __restrict__ out)
{
  const int t = threadIdx.x;
  const int r = blockIdx.x*16 + (t >> 4);      // global row 0..16383
  const int c0 = (t & 15)*8;
  const int qbn = r >> 6, rr = r & 63;
  float m[4], l[4], M = -1e30f;
  #pragma unroll
  for (int s=0; s<4; s++){
    float2 v = ml[((size_t)qbn*4 + s)*64 + rr];
    m[s] = v.x; l[s] = v.y;
    M = fmaxf(M, m[s]);
  }
  float L = 0.f;
  #pragma unroll
  for (int s=0; s<4; s++){ m[s] = exp2f(m[s] - M); L += l[s]*m[s]; }
  const float inv = 1.0f / L;
  float acc[8] = {0,0,0,0,0,0,0,0};
  #pragma unroll
  for (int s=0; s<4; s++){
    short8 o = *(const short8*)(Opart + (((size_t)qbn*4 + s)*64 + rr)*(size_t)HD + c0);
    float sc = m[s]*inv;
    #pragma unroll
    for (int j=0;j<8;j++) acc[j] += bf2f((u16)o[j]) * sc;
  }
  f32x4 o0 = f32x4{acc[0],acc[1],acc[2],acc[3]};
  f32x4 o1 = f32x4{acc[4],acc[5],acc[6],acc[7]};
  *(f32x4*)(out + (size_t)r*HD + c0)     = o0;
  *(f32x4*)(out + (size_t)r*HD + c0 + 4) = o1;
}

extern "C" void kernel_launch(void* const* d_in, const int* in_sizes, int n_in,
                              void* d_out, int out_size, void* d_ws, size_t ws_size,
                              hipStream_t stream){
  const float* x  = (const float*)d_in[0];
  const float* wq = (const float*)d_in[1];
  const float* wk = (const float*)d_in[2];
  const float* wv = (const float*)d_in[3];
  float* out = (float*)d_out;
  char* ws = (char*)d_ws;

  size_t off = 0;
  u16* xb = (u16*)(ws + off); off += (size_t)BS*DMODEL*2;       // 64 MB
  u16* wb = (u16*)(ws + off); off += (size_t)3*HD*DMODEL*2;     // 1.5 MB
  float2* tab = (float2*)(ws + off); off += (size_t)SEQ*64*8;   // 2 MB
  u16* qb = (u16*)(ws + off); off += (size_t)BS*HD*2;           // 4 MB
  u16* kb = (u16*)(ws + off); off += (size_t)BS*HD*2;           // 4 MB
  u16* vt = (u16*)(ws + off); off += (size_t)BS*HD*2;           // 4 MB
  u16* Opart = (u16*)(ws + off); off += (size_t)1024*64*HD*2;   // 16.8 MB
  float2* ml = (float2*)(ws + off); off += (size_t)1024*64*8;   // 0.5 MB
  if (ws_size < off) return;  // insufficient workspace -> fail visibly

  hipLaunchKernelGGL(k_prep, dim3(4096),   dim3(256), 0, stream, tab, wq, wk, wv, wb);
  hipLaunchKernelGGL(k_cvtx, dim3(16384),  dim3(256), 0, stream, x, xb);
  hipLaunchKernelGGL(k_gemm, dim3(3,256),  dim3(256), 0, stream, xb, wb, tab, qb, kb, vt);
  hipLaunchKernelGGL(k_attn, dim3(1024),   dim3(256), 0, stream, qb, kb, vt, Opart, ml);
  hipLaunchKernelGGL(k_comb, dim3(1024),   dim3(256), 0, stream, Opart, ml, out);
}

// Round 13
// 122.378 us; speedup vs baseline: 1.0981x; 1.0981x over previous
//
#include <hip/hip_runtime.h>
#include <hip/hip_bf16.h>

#define BATCH 4
#define SEQ 4096
#define DMODEL 2048
#define HD 128
#define BS (BATCH*SEQ)

typedef __attribute__((ext_vector_type(8))) short short8;
typedef __attribute__((ext_vector_type(4))) float f32x4;
typedef __attribute__((ext_vector_type(4))) float float4v;
typedef unsigned short u16;
typedef unsigned int u32;

#define LOG2E 1.4426950408889634f
#define SCALE 0.08838834764831845f /* 1/sqrt(128) */

__device__ __forceinline__ u16 f2bf(float f){
  u32 u = __builtin_bit_cast(u32, f);
  u32 r = (u + 0x7FFFu + ((u >> 16) & 1u)) >> 16;
  return (u16)r;
}
__device__ __forceinline__ float bf2f(u16 b){
  u32 u = ((u32)b) << 16;
  return __builtin_bit_cast(float, u);
}

__device__ __forceinline__ void gload16(const void* gptr, void* lptr){
  __builtin_amdgcn_global_load_lds((const __attribute__((address_space(1))) void*)gptr,
                                   (__attribute__((address_space(3))) void*)lptr, 16, 0, 0);
}

// ---------------- trig table + weight convert, merged ----------------
__global__ __launch_bounds__(256) void k_prep(float2* __restrict__ tab,
                                              const float* __restrict__ wq, const float* __restrict__ wk,
                                              const float* __restrict__ wv, u16* __restrict__ wb){
  int bidx = blockIdx.x;
  if (bidx < 1024){
    int i = bidx*256 + threadIdx.x;            // 4096*64 total
    int s = i >> 6, j = i & 63;
    float invf = (float)pow(10000.0, -(double)j/64.0);
    float ang  = (float)s * invf;              // mimic fp32 reference rounding of the angle
    double a = (double)ang;
    tab[i] = make_float2((float)cos(a), (float)sin(a));
  } else {
    int i = (bidx - 1024)*256 + threadIdx.x;   // 3*262144 total
    int m = i >> 18; int r = i & 262143;
    const float* s = (m==0) ? wq : ((m==1) ? wk : wv);
    wb[i] = f2bf(s[r]);
  }
}

// ---------------- fused QKV projection GEMM (r6-validated, 77us) + RoPE / V^T epilogue ----
// grid 512: 32-row M-tile, all 384 cols (Q|K|V). 4 waves, each 32 rows x 96 cols.
// LDS 56KB (A bf16 dbuf 2x4KB + W 48KB single-buf) -> 2 blocks/CU, 8 waves/CU.
// Issue order per iter: W (12 gload_lds) THEN A prefetch, so vmcnt(2) retires all W and
// leaves only the 2 newest A loads in flight. sched_barrier(0) pins phase boundaries.
__global__ __launch_bounds__(256) void k_gemm(
    const float* __restrict__ x, const u16* __restrict__ wb, const float2* __restrict__ tab,
    u16* __restrict__ qb, u16* __restrict__ kb, u16* __restrict__ vt)
{
  __shared__ char lds[8192 + 49152];   // [0..8191] A dbuf (2x4KB), [8192..] W 48KB
  const int tid = threadIdx.x;
  const size_t M0 = (size_t)blockIdx.x * 32;
  const int w = tid >> 6, lane = tid & 63, lr = lane & 15, lg = lane >> 4;
  const int h = w & 1, g = w >> 1;

  // N-frag slots: [0..3] = rope pairs (lo0,hi0,lo1,hi1), [4..5] = V
  int nfs[6];
  nfs[0] = g*8 + 2*h;     nfs[1] = nfs[0] + 4;
  nfs[2] = g*8 + 2*h + 1; nfs[3] = nfs[2] + 4;
  nfs[4] = 16 + 2*w;      nfs[5] = nfs[4] + 1;

  // A staging: thread handles 8 consecutive fp32 of the 32x64 tile
  const int arow = tid >> 3, acol = (tid & 7)*8;
  const float* axp = x + (M0 + arow)*DMODEL + acol;
  const int awbyte = arow*128 + ((acol*2) ^ ((arow & 7) << 4));

  // W staging: 12 gload16/thread, preswizzled source
  int woff[12], wdst[12];
  #pragma unroll
  for (int i=0;i<12;i++){
    int L = i*4096 + tid*16;
    int row = L >> 7, cb = L & 127;
    int scb = cb ^ ((row & 7) << 4);
    woff[i] = row*DMODEL + (scb >> 1);
    wdst[i] = 8192 + L;
  }

  f32x4 acc[2][6];
  #pragma unroll
  for (int i=0;i<2;i++)
    #pragma unroll
    for (int j=0;j<6;j++) acc[i][j] = f32x4{0.f,0.f,0.f,0.f};

  float4v s0a, s0b, s1a, s1b;   // prefetch slots (tile parity 0 / 1)

  // ---- prologue: A(0); W(0); A(1); cvt A(0); vmcnt(2) leaves A(1) in flight ----
  s0a = *(const float4v*)(axp);      s0b = *(const float4v*)(axp + 4);
  __builtin_amdgcn_sched_barrier(0);
  #pragma unroll
  for (int i=0;i<12;i++) gload16(wb + woff[i], lds + wdst[i]);
  __builtin_amdgcn_sched_barrier(0);
  s1a = *(const float4v*)(axp + 64); s1b = *(const float4v*)(axp + 68);
  __builtin_amdgcn_sched_barrier(0);
  {
    short8 o;
    o[0]=(short)f2bf(s0a[0]); o[1]=(short)f2bf(s0a[1]); o[2]=(short)f2bf(s0a[2]); o[3]=(short)f2bf(s0a[3]);
    o[4]=(short)f2bf(s0b[0]); o[5]=(short)f2bf(s0b[1]); o[6]=(short)f2bf(s0b[2]); o[7]=(short)f2bf(s0b[3]);
    *(short8*)(lds + awbyte) = o;
  }
  __builtin_amdgcn_sched_barrier(0);
  asm volatile("s_waitcnt vmcnt(2) lgkmcnt(0)" ::: "memory");
  __builtin_amdgcn_sched_barrier(0);
  __builtin_amdgcn_s_barrier();
  __builtin_amdgcn_sched_barrier(0);

  for (int t=0; t<31; t++){
    const int p = t & 1;
    // [2] compute tile t from bufA[p] + W(t)
    {
      const char* lA = lds + p*4096;
      const char* lW = lds + 8192;
      short8 af[2][2];
      #pragma unroll
      for (int ks=0;ks<2;ks++)
        #pragma unroll
        for (int rf=0;rf<2;rf++){
          int r = rf*16 + lr;
          af[ks][rf] = *(const short8*)(lA + r*128 + ((ks*64 + lg*16) ^ ((r&7)<<4)));
        }
      #pragma unroll
      for (int j=0;j<6;j++){
        int rw = nfs[j]*16 + lr;
        #pragma unroll
        for (int ks=0;ks<2;ks++){
          short8 bf = *(const short8*)(lW + rw*128 + ((ks*64 + lg*16) ^ ((lr&7)<<4)));
          #pragma unroll
          for (int rf=0;rf<2;rf++)
            acc[rf][j] = __builtin_amdgcn_mfma_f32_16x16x32_bf16(af[ks][rf], bf, acc[rf][j], 0,0,0);
        }
      }
    }
    // [3] all waves done reading W(t) and bufA[p]
    __builtin_amdgcn_sched_barrier(0);
    __builtin_amdgcn_s_barrier();
    __builtin_amdgcn_sched_barrier(0);
    // [4] issue W(t+1)  (12 global_load_lds — must be OLDER than the A prefetch)
    const int k0 = (t+1)*64;
    #pragma unroll
    for (int i=0;i<12;i++) gload16(wb + woff[i] + k0, lds + wdst[i]);
    __builtin_amdgcn_sched_barrier(0);
    // [1'] issue A(t+2) into slot p (clamped at the tail; redundancy keeps vmcnt uniform)
    {
      const float* ap = axp + (t+2 <= 31 ? (t+2)*64 : 31*64);
      float4v na = *(const float4v*)(ap), nb = *(const float4v*)(ap + 4);
      if (p == 0){ s0a = na; s0b = nb; } else { s1a = na; s1b = nb; }
    }
    __builtin_amdgcn_sched_barrier(0);
    // [5] cvt A(t+1) (slot p^1; compiler auto-waits those oldest loads) -> bufA[p^1]
    {
      float4v ca, cb2;
      if (p == 0){ ca = s1a; cb2 = s1b; } else { ca = s0a; cb2 = s0b; }
      short8 o;
      o[0]=(short)f2bf(ca[0]);  o[1]=(short)f2bf(ca[1]);  o[2]=(short)f2bf(ca[2]);  o[3]=(short)f2bf(ca[3]);
      o[4]=(short)f2bf(cb2[0]); o[5]=(short)f2bf(cb2[1]); o[6]=(short)f2bf(cb2[2]); o[7]=(short)f2bf(cb2[3]);
      *(short8*)(lds + (p^1)*4096 + awbyte) = o;
    }
    __builtin_amdgcn_sched_barrier(0);
    // [6] W(t+1) + ds_writes complete; only A(t+2)'s 2 loads stay in flight
    asm volatile("s_waitcnt vmcnt(2) lgkmcnt(0)" ::: "memory");
    __builtin_amdgcn_sched_barrier(0);
    __builtin_amdgcn_s_barrier();
    __builtin_amdgcn_sched_barrier(0);
  }
  // final tile 31 compute
  {
    const char* lA = lds + (31 & 1)*4096;
    const char* lW = lds + 8192;
    short8 af[2][2];
    #pragma unroll
    for (int ks=0;ks<2;ks++)
      #pragma unroll
      for (int rf=0;rf<2;rf++){
        int r = rf*16 + lr;
        af[ks][rf] = *(const short8*)(lA + r*128 + ((ks*64 + lg*16) ^ ((r&7)<<4)));
      }
    #pragma unroll
    for (int j=0;j<6;j++){
      int rw = nfs[j]*16 + lr;
      #pragma unroll
      for (int ks=0;ks<2;ks++){
        short8 bf = *(const short8*)(lW + rw*128 + ((ks*64 + lg*16) ^ ((lr&7)<<4)));
        #pragma unroll
        for (int rf=0;rf<2;rf++)
          acc[rf][j] = __builtin_amdgcn_mfma_f32_16x16x32_bf16(af[ks][rf], bf, acc[rf][j], 0,0,0);
      }
    }
  }

  // epilogue: RoPE on Q/K pairs, V transposed store
  u16* dst = (g == 0) ? qb : kb;
  #pragma unroll
  for (int rf=0; rf<2; rf++)
    #pragma unroll
    for (int reg=0; reg<4; reg++){
      size_t grow = M0 + rf*16 + lg*4 + reg;
      int spos = (int)(grow & (SEQ-1));
      size_t b = grow >> 12;
      #pragma unroll
      for (int p=0; p<2; p++){
        int j = (2*h + p)*16 + lr;
        float2 cs = tab[spos*64 + j];
        float lo = acc[rf][2*p][reg];
        float hi = acc[rf][2*p+1][reg];
        dst[grow*HD + j]      = f2bf(lo*cs.x - hi*cs.y);
        dst[grow*HD + j + 64] = f2bf(hi*cs.x + lo*cs.y);
      }
      #pragma unroll
      for (int jj=0; jj<2; jj++){
        int col = (2*w + jj)*16 + lr;
        vt[(b*HD + col)*SEQ + spos] = f2bf(acc[rf][4+jj][reg]);
      }
    }
}

// ---------------- causal flash attention, 4-way KV split (flash-decoding) ----------------
// grid 1024: (batch, 64-row q-tile, kv-split). 4 waves x 16 q-rows share staged lK/lV.
// LDS 40KB -> 4 blocks/CU -> 16 waves/CU. Partials (O bf16, ml fp32) to workspace.
__global__ __launch_bounds__(256) void k_attn(
    const u16* __restrict__ qbuf, const u16* __restrict__ kb, const u16* __restrict__ vt,
    u16* __restrict__ Opart, float2* __restrict__ ml)
{
  __shared__ u16 lK[64*128];    // byte = kv*256 + (cb ^ ((kv&7)<<4))
  __shared__ u16 lV[128*64];    // byte = d*128  + (cb ^ ((d&7)<<4))
  __shared__ u16 lP[4][16*64];  // per-wave, byte = r*128 + (cb ^ ((r&7)<<4))
  const int tid = threadIdx.x;
  const int bid = blockIdx.x;
  const int x = bid & 7, idx = bid >> 3;
  const int b = x >> 1, half = x & 1;
  const int qt = 63 - (idx >> 1);              // heavy tiles first
  const int sp = (idx & 1) + 2*half;           // kv-split 0..3
  const int qbn = b*64 + qt;                   // 0..255
  const int w = tid >> 6, lane = tid & 63, lr = lane & 15, lg = lane >> 4;

  // balanced contiguous partition of tiles [0, qt] into 4 chunks
  const int n = qt + 1, cbase = n >> 2, crem = n & 3;
  const int cnt = cbase + (sp < crem ? 1 : 0);
  const int klo = sp*cbase + (sp < crem ? sp : crem);
  const int khi = klo + cnt;
  const size_t prow0 = ((size_t)qbn*4 + sp)*64;

  if (cnt == 0){                               // empty split: mark and exit (block-uniform)
    if (lr == 0){
      #pragma unroll
      for (int reg=0; reg<4; reg++)
        ml[prow0 + w*16 + lg*4 + reg] = make_float2(-1e30f, 0.f);
    }
    return;
  }

  const size_t qrow = (size_t)b*SEQ + qt*64 + w*16 + lr;
  short8 aq[4];
  #pragma unroll
  for (int ks=0; ks<4; ks++)
    aq[ks] = *(const short8*)(qbuf + qrow*HD + ks*32 + lg*8);

  f32x4 accO[8];
  #pragma unroll
  for (int i=0;i<8;i++) accO[i] = f32x4{0.f,0.f,0.f,0.f};
  float m2[4]   = {-1e30f,-1e30f,-1e30f,-1e30f};
  float lsum[4] = {0.f,0.f,0.f,0.f};

  const int Lb = tid*16;
  const float cfac = SCALE * LOG2E;

  for (int kt = klo; kt < khi; kt++){
    #pragma unroll
    for (int i=0;i<4;i++){
      int L = i*4096 + Lb;
      { int row = L >> 8, cb = L & 255;
        int scb = cb ^ ((row & 7) << 4);
        gload16(kb + ((size_t)b*SEQ + kt*64 + row)*HD + (scb>>1), ((char*)lK) + L); }
      { int row = L >> 7, cb = L & 127;
        int scb = cb ^ ((row & 7) << 4);
        gload16(vt + ((size_t)b*HD + row)*SEQ + kt*64 + (scb>>1), ((char*)lV) + L); }
    }
    __syncthreads();

    // S = Q K^T  (16 q-rows x 64 kv) in log2-domain units
    f32x4 sc[4];
    #pragma unroll
    for (int nf=0; nf<4; nf++){
      sc[nf] = f32x4{0.f,0.f,0.f,0.f};
      #pragma unroll
      for (int ks=0; ks<4; ks++){
        int r = nf*16 + lr;
        int byte = r*256 + ((ks*64 + lg*16) ^ ((r&7)<<4));
        short8 bk = *(const short8*)((const char*)lK + byte);
        sc[nf] = __builtin_amdgcn_mfma_f32_16x16x32_bf16(aq[ks], bk, sc[nf], 0,0,0);
      }
      sc[nf] *= cfac;
    }
    if (kt == qt){                            // diagonal tile: causal mask
      #pragma unroll
      for (int nf=0; nf<4; nf++)
        #pragma unroll
        for (int reg=0; reg<4; reg++){
          int col = nf*16 + lr;
          int row = w*16 + lg*4 + reg;
          if (col > row) sc[nf][reg] = -1e30f;
        }
    }
    float al[4];
    #pragma unroll
    for (int reg=0; reg<4; reg++){
      float v = fmaxf(fmaxf(sc[0][reg], sc[1][reg]), fmaxf(sc[2][reg], sc[3][reg]));
      v = fmaxf(v, __shfl_xor(v, 1));
      v = fmaxf(v, __shfl_xor(v, 2));
      v = fmaxf(v, __shfl_xor(v, 4));
      v = fmaxf(v, __shfl_xor(v, 8));
      float mnew = fmaxf(m2[reg], v);
      al[reg] = exp2f(m2[reg] - mnew);
      m2[reg] = mnew;
    }
    float prs[4] = {0.f,0.f,0.f,0.f};
    #pragma unroll
    for (int nf=0; nf<4; nf++)
      #pragma unroll
      for (int reg=0; reg<4; reg++){
        float p = exp2f(sc[nf][reg] - m2[reg]);
        prs[reg] += p;
        int r = lg*4 + reg;
        int byte = r*128 + ((nf*32 + lr*2) ^ ((r&7)<<4));
        *(u16*)(((char*)lP[w]) + byte) = f2bf(p);
      }
    f32x4 alv = f32x4{al[0], al[1], al[2], al[3]};
    #pragma unroll
    for (int reg=0; reg<4; reg++){
      float v = prs[reg];
      v += __shfl_xor(v, 1);
      v += __shfl_xor(v, 2);
      v += __shfl_xor(v, 4);
      v += __shfl_xor(v, 8);
      lsum[reg] = lsum[reg]*al[reg] + v;
    }
    #pragma unroll
    for (int cf=0; cf<8; cf++) accO[cf] *= alv;

    short8 pa[2];
    #pragma unroll
    for (int ks=0; ks<2; ks++){
      int byte = lr*128 + ((ks*64 + lg*16) ^ ((lr&7)<<4));
      pa[ks] = *(const short8*)(((const char*)lP[w]) + byte);
    }
    #pragma unroll
    for (int cf=0; cf<8; cf++){
      #pragma unroll
      for (int ks=0; ks<2; ks++){
        int d = cf*16 + lr;
        int byte = d*128 + ((ks*64 + lg*16) ^ ((d&7)<<4));
        short8 bv = *(const short8*)(((const char*)lV) + byte);
        accO[cf] = __builtin_amdgcn_mfma_f32_16x16x32_bf16(pa[ks], bv, accO[cf], 0,0,0);
      }
    }
    __syncthreads();
  }

  // partial epilogue: bf16 accO + (m, l) per row
  #pragma unroll
  for (int reg=0; reg<4; reg++){
    size_t pr = prow0 + w*16 + lg*4 + reg;
    #pragma unroll
    for (int cf=0; cf<8; cf++)
      Opart[pr*HD + cf*16 + lr] = f2bf(accO[cf][reg]);
  }
  if (lr == 0){
    #pragma unroll
    for (int reg=0; reg<4; reg++)
      ml[prow0 + w*16 + lg*4 + reg] = make_float2(m2[reg], lsum[reg]);
  }
}

// ---------------- combine partials: out = sum_s O_s * 2^(m_s-M) / L ----------------
// grid 1024: 16 rows/block, 8 cols/thread (bf16 Opart short8 reads).
__global__ __launch_bounds__(256) void k_comb(
    const u16* __restrict__ Opart, const float2* __restrict__ ml, float* __restrict__ out)
{
  const int t = threadIdx.x;
  const int r = blockIdx.x*16 + (t >> 4);      // global row 0..16383
  const int c0 = (t & 15)*8;
  const int qbn = r >> 6, rr = r & 63;
  float m[4], l[4], M = -1e30f;
  #pragma unroll
  for (int s=0; s<4; s++){
    float2 v = ml[((size_t)qbn*4 + s)*64 + rr];
    m[s] = v.x; l[s] = v.y;
    M = fmaxf(M, m[s]);
  }
  float L = 0.f;
  #pragma unroll
  for (int s=0; s<4; s++){ m[s] = exp2f(m[s] - M); L += l[s]*m[s]; }
  const float inv = 1.0f / L;
  float acc[8] = {0,0,0,0,0,0,0,0};
  #pragma unroll
  for (int s=0; s<4; s++){
    short8 o = *(const short8*)(Opart + (((size_t)qbn*4 + s)*64 + rr)*(size_t)HD + c0);
    float sc = m[s]*inv;
    #pragma unroll
    for (int j=0;j<8;j++) acc[j] += bf2f((u16)o[j]) * sc;
  }
  f32x4 o0 = f32x4{acc[0],acc[1],acc[2],acc[3]};
  f32x4 o1 = f32x4{acc[4],acc[5],acc[6],acc[7]};
  *(f32x4*)(out + (size_t)r*HD + c0)     = o0;
  *(f32x4*)(out + (size_t)r*HD + c0 + 4) = o1;
}

extern "C" void kernel_launch(void* const* d_in, const int* in_sizes, int n_in,
                              void* d_out, int out_size, void* d_ws, size_t ws_size,
                              hipStream_t stream){
  const float* x  = (const float*)d_in[0];
  const float* wq = (const float*)d_in[1];
  const float* wk = (const float*)d_in[2];
  const float* wv = (const float*)d_in[3];
  float* out = (float*)d_out;
  char* ws = (char*)d_ws;

  size_t off = 0;
  u16* wb = (u16*)(ws + off); off += (size_t)3*HD*DMODEL*2;     // 1.5 MB
  float2* tab = (float2*)(ws + off); off += (size_t)SEQ*64*8;   // 2 MB
  u16* qb = (u16*)(ws + off); off += (size_t)BS*HD*2;           // 4 MB
  u16* kb = (u16*)(ws + off); off += (size_t)BS*HD*2;           // 4 MB
  u16* vt = (u16*)(ws + off); off += (size_t)BS*HD*2;           // 4 MB
  u16* Opart = (u16*)(ws + off); off += (size_t)1024*64*HD*2;   // 16.8 MB
  float2* ml = (float2*)(ws + off); off += (size_t)1024*64*8;   // 0.5 MB
  if (ws_size < off) return;  // insufficient workspace -> fail visibly

  hipLaunchKernelGGL(k_prep, dim3(4096),  dim3(256), 0, stream, tab, wq, wk, wv, wb);
  hipLaunchKernelGGL(k_gemm, dim3(512),   dim3(256), 0, stream, x, wb, tab, qb, kb, vt);
  hipLaunchKernelGGL(k_attn, dim3(1024),  dim3(256), 0, stream, qb, kb, vt, Opart, ml);
  hipLaunchKernelGGL(k_comb, dim3(1024),  dim3(256), 0, stream, Opart, ml, out);
}